// Round 2
// baseline (2433.405 us; speedup 1.0000x reference)
//
#include <hip/hip_runtime.h>

#define Bv 4
#define Nv 20000
#define Sv 9
#define Pv (Bv*Nv)

// ws float offsets (wsum tables only)
#define OFF_NS1 0
#define OFF_NS2 192
#define OFF_AS1 384
#define OFF_AS2 576

// wsum[k][o] = sum_c w[k][c][o]  (channel-sum trick for x + sum(x,-1))
__global__ void setup_wsum(const float* __restrict__ nw1, const float* __restrict__ nw2,
                           const float* __restrict__ aw1, const float* __restrict__ aw2,
                           float* __restrict__ ws)
{
  int tid = blockIdx.x*blockDim.x + threadIdx.x;
  const float* srcs[4] = {nw1, nw2, aw1, aw2};
  for (int t=0;t<4;t++){
    const float* W = srcs[t];
    for (int i=tid;i<192;i+=gridDim.x*blockDim.x){
      int k=i>>6, o=i&63; float s=0.f;
      for (int c=0;c<64;c++) s += W[(k*64+c)*64+o];
      ws[t*192+i]=s;
    }
  }
}

// ib: CIN rows of [12] (index i = s+1, zero pads at 0,10,11)
// rb: this wave's 64x12 LDS buffer (pads pre-zeroed); lane = output channel
template<int CIN>
__device__ __forceinline__ void encode(
    const float (*ib)[12], float (*rb)[12],
    const float* __restrict__ w0, const float* __restrict__ b0,
    const float* __restrict__ w1, const float* __restrict__ b1, const float* __restrict__ s1,
    const float* __restrict__ w2, const float* __restrict__ b2, const float* __restrict__ s2,
    int lane)
{
  float r[Sv];
  // ---- layer 0: r = relu(conv(x + sum_c x, w0) + b0) ----
  {
    float xv[CIN][11];
    #pragma unroll
    for (int i=0;i<11;i++){
      float v[CIN]; float sum = 0.f;
      #pragma unroll
      for (int ch=0;ch<CIN;ch++){ v[ch] = ib[ch][i]; sum += v[ch]; }
      #pragma unroll
      for (int ch=0;ch<CIN;ch++) xv[ch][i] = v[ch] + sum;
    }
    float wr[3][CIN];
    #pragma unroll
    for (int k=0;k<3;k++)
      #pragma unroll
      for (int ch=0;ch<CIN;ch++) wr[k][ch] = w0[(k*CIN+ch)*64 + lane];
    float bias = b0[lane];
    #pragma unroll
    for (int s=0;s<Sv;s++){
      float a = bias;
      #pragma unroll
      for (int k=0;k<3;k++)
        #pragma unroll
        for (int ch=0;ch<CIN;ch++) a += xv[ch][s+k]*wr[k][ch];
      r[s] = fmaxf(a, 0.f);
      rb[lane][1+s] = r[s];
    }
  }
  // ---- layers 1,2: r = r + relu(conv(r + sum_c r, w) + b) ----
  #pragma unroll 1
  for (int L=0;L<2;L++){
    const float* W  = L ? w2 : w1;
    const float* bb = L ? b2 : b1;
    const float* su = L ? s2 : s1;
    // rowsum over channels (all 64 lanes) per s
    float rs[Sv];
    #pragma unroll
    for (int s=0;s<Sv;s++){
      float v = r[s];
      #pragma unroll
      for (int m=1;m<64;m<<=1) v += __shfl_xor(v, m);
      rs[s]=v;
    }
    float u0 = su[lane], u1 = su[64+lane], u2 = su[128+lane];
    float bias = bb[lane];
    float acc[Sv];
    #pragma unroll
    for (int s=0;s<Sv;s++){
      float a = bias + rs[s]*u1;
      if (s>0)    a += rs[s-1]*u0;
      if (s<Sv-1) a += rs[s+1]*u2;
      acc[s]=a;
    }
    #pragma unroll 4
    for (int c=0;c<64;c++){
      float4 xa = *(const float4*)&rb[c][0];   // lane-uniform addr -> LDS broadcast
      float4 xb = *(const float4*)&rb[c][4];
      float4 xc = *(const float4*)&rb[c][8];
      float wa = W[(0*64+c)*64+lane];
      float wb = W[(64+c)*64+lane];
      float wc = W[(128+c)*64+lane];
      float x0=xa.x,x1=xa.y,x2=xa.z,x3=xa.w,x4=xb.x,x5=xb.y,x6=xb.z,x7=xb.w,x8=xc.x,x9=xc.y,x10=xc.z;
      acc[0] += x0*wa + x1*wb + x2*wc;
      acc[1] += x1*wa + x2*wb + x3*wc;
      acc[2] += x2*wa + x3*wb + x4*wc;
      acc[3] += x3*wa + x4*wb + x5*wc;
      acc[4] += x4*wa + x5*wb + x6*wc;
      acc[5] += x5*wa + x6*wb + x7*wc;
      acc[6] += x6*wa + x7*wb + x8*wc;
      acc[7] += x7*wa + x8*wb + x9*wc;
      acc[8] += x8*wa + x9*wb + x10*wc;
    }
    #pragma unroll
    for (int s=0;s<Sv;s++) r[s] += fmaxf(acc[s], 0.f);
    #pragma unroll
    for (int s=0;s<Sv;s++) rb[lane][1+s] = r[s];   // in-place OK: same-wave DS ops are ordered
  }
}

#define WVS 4

__global__ __launch_bounds__(256) void locse_main(
    const float* __restrict__ pc, const float* __restrict__ feats,
    const float* __restrict__ nw0, const float* __restrict__ nb0,
    const float* __restrict__ nw1, const float* __restrict__ nb1,
    const float* __restrict__ nw2, const float* __restrict__ nb2,
    const float* __restrict__ aw0, const float* __restrict__ ab0,
    const float* __restrict__ aw1, const float* __restrict__ ab1,
    const float* __restrict__ aw2, const float* __restrict__ ab2,
    const float* __restrict__ mw,  const float* __restrict__ mb,
    const float* __restrict__ ws, float* __restrict__ out)
{
  __shared__ __align__(16) float rbuf[WVS][2][64][12];
  __shared__ __align__(16) float inb[WVS][4][12];
  const int lane = threadIdx.x & 63;
  const int wid  = threadIdx.x >> 6;
  const int gw   = blockIdx.x*WVS + wid;
  const int nw   = gridDim.x*WVS;

  float (*rb0)[12] = rbuf[wid][0];
  float (*rb1)[12] = rbuf[wid][1];
  float (*ib)[12]  = inb[wid];

  // zero pads once (rows rewritten at idx 1..9 per point; idx 0,10,11 stay 0)
  #pragma unroll
  for (int j=0;j<12;j++){ rb0[lane][j]=0.f; rb1[lane][j]=0.f; }
  if (lane < 48) ((float*)ib)[lane] = 0.f;

  for (int p = gw; p < Pv; p += nw){
    float x0=0.f,x1=0.f,x2=0.f,x3=0.f;
    if (lane < Sv){
      const float4 v = *(const float4*)(pc + ((size_t)p*Sv + lane)*4);
      x0=v.x; x1=v.y; x2=v.z; x3=v.w;
    }
    const float c0=__shfl(x0,0), c1=__shfl(x1,0), c2=__shfl(x2,0), c3=__shfl(x3,0);
    if (lane < Sv){
      float d0=c0-x0, d1=c1-x1;
      float n2=x0*x0+x1*x1;
      float nrm = n2>0.f ? sqrtf(n2) : 0.f;
      float dn2=d0*d0+d1*d1;
      float dn = dn2>0.f ? sqrtf(dn2) : 0.f;
      float cn2=c0*c0+c1*c1+c2*c2+c3*c3;
      float cn = cn2>0.f ? sqrtf(cn2) : 0.f;
      float num = d0*c2+d1*c3;
      float den = dn*cn + 1e-8f;
      float ang = 1.f - fabsf(num/den);
      ib[0][1+lane]=d0;   // nrm_in  = diff ch0
      ib[1][1+lane]=d1;   // ang ch0 = diff ch1
      ib[2][1+lane]=nrm;  // ang ch1 = norms
      ib[3][1+lane]=ang;  // ang ch2 = angles
    }
    encode<1>(&ib[0], rb0, nw0, nb0, nw1, nb1, ws+OFF_NS1, nw2, nb2, ws+OFF_NS2, lane);
    encode<3>(&ib[1], rb1, aw0, ab0, aw1, ab1, ws+OFF_AS1, aw2, ab2, ws+OFF_AS2, lane);
    // ---- MLP: relu(concat(nrm_e, ang_e) @ mlp_w + mlp_b) ----
    float acc[Sv];
    {
      float bias = mb[lane];
      #pragma unroll
      for (int s=0;s<Sv;s++) acc[s]=bias;
      #pragma unroll 4
      for (int c=0;c<64;c++){
        float4 xa=*(const float4*)&rb0[c][0];
        float4 xb=*(const float4*)&rb0[c][4];
        float4 xc=*(const float4*)&rb0[c][8];
        float w = mw[c*64+lane];
        float e1=xa.y,e2=xa.z,e3=xa.w,e4=xb.x,e5=xb.y,e6=xb.z,e7=xb.w,e8=xc.x,e9=xc.y;
        acc[0]+=e1*w; acc[1]+=e2*w; acc[2]+=e3*w; acc[3]+=e4*w; acc[4]+=e5*w;
        acc[5]+=e6*w; acc[6]+=e7*w; acc[7]+=e8*w; acc[8]+=e9*w;
      }
      #pragma unroll 4
      for (int c=0;c<64;c++){
        float4 xa=*(const float4*)&rb1[c][0];
        float4 xb=*(const float4*)&rb1[c][4];
        float4 xc=*(const float4*)&rb1[c][8];
        float w = mw[(64+c)*64+lane];
        float e1=xa.y,e2=xa.z,e3=xa.w,e4=xb.x,e5=xb.y,e6=xb.z,e7=xb.w,e8=xc.x,e9=xc.y;
        acc[0]+=e1*w; acc[1]+=e2*w; acc[2]+=e3*w; acc[3]+=e4*w; acc[4]+=e5*w;
        acc[5]+=e6*w; acc[6]+=e7*w; acc[7]+=e8*w; acc[8]+=e9*w;
      }
    }
    const size_t ob = (size_t)p*Sv*128;
    const size_t fb = (size_t)p*Sv*64;
    #pragma unroll
    for (int s=0;s<Sv;s++){
      out[ob + s*128 + lane]      = fmaxf(acc[s],0.f);
      out[ob + s*128 + 64 + lane] = feats[fb + s*64 + lane];   // passthrough
    }
  }
}

extern "C" void kernel_launch(void* const* d_in, const int* in_sizes, int n_in,
                              void* d_out, int out_size, void* d_ws, size_t ws_size,
                              hipStream_t stream)
{
  const float* pc    = (const float*)d_in[0];
  const float* feats = (const float*)d_in[1];
  const float* nw0=(const float*)d_in[14]; const float* nb0=(const float*)d_in[15];
  const float* nw1=(const float*)d_in[16]; const float* nb1=(const float*)d_in[17];
  const float* nw2=(const float*)d_in[18]; const float* nb2=(const float*)d_in[19];
  const float* aw0=(const float*)d_in[20]; const float* ab0=(const float*)d_in[21];
  const float* aw1=(const float*)d_in[22]; const float* ab1=(const float*)d_in[23];
  const float* aw2=(const float*)d_in[24]; const float* ab2=(const float*)d_in[25];
  const float* mw =(const float*)d_in[26]; const float* mb =(const float*)d_in[27];
  float* ws = (float*)d_ws;
  float* out = (float*)d_out;

  setup_wsum<<<4, 256, 0, stream>>>(nw1, nw2, aw1, aw2, ws);
  locse_main<<<2500, 256, 0, stream>>>(pc, feats,
      nw0,nb0,nw1,nb1,nw2,nb2, aw0,ab0,aw1,ab1,aw2,ab2, mw,mb, ws, out);
}

// Round 3
// 826.563 us; speedup vs baseline: 2.9440x; 2.9440x over previous
//
#include <hip/hip_runtime.h>

typedef _Float16 f16;
typedef f16 half8 __attribute__((ext_vector_type(8)));
typedef float f32x4 __attribute__((ext_vector_type(4)));

#define Pv 80000
#define G 7              // points per wave (63 GEMM rows -> 4 M-tiles of 16, 1 garbage row)
#define AST 72           // LDS activation row stride in f16 (72*2B=144B -> rows shift 4 banks; 2-way max conflict = free)
#define NGRP 11429       // ceil(80000/7)

// ws (f16) layout:
//   conv frags [L(4)][nt(4)][q(7)][lane(64)][8]   L: 0=ang1,1=ang2,2=nrm1,3=nrm2   (14336 f16 per layer)
//   mlp  frags [nt(4)][q(4)][lane(64)][8] at f16 offset 57344
// B-frag element (q<6): k = q*32 + (lane>>4)*8 + j  (k = tap*64+c, tap-major) -> W[k*64+n], n = nt*16+(lane&15)
// q==6: k=192..194 -> wsum[tap][n] (channel-sum trick as extra K-step); k>=195 -> 0.

__global__ void setup_frags(const float* __restrict__ aw1, const float* __restrict__ aw2,
                            const float* __restrict__ nw1, const float* __restrict__ nw2,
                            const float* __restrict__ mlp_w, f16* __restrict__ ws)
{
  int tid = blockIdx.x*blockDim.x + threadIdx.x;   // 8192 threads
  if (tid < 7168){
    int L    = tid / 1792;
    int rem  = tid % 1792;           // nt*448 + q*64 + lane
    int q    = (rem % 448) / 64;
    int lane = rem % 64;
    int nt   = rem / 448;
    const float* W = (L==0)?aw1:(L==1)?aw2:(L==2)?nw1:nw2;
    int n = nt*16 + (lane & 15);
    f16 o8[8];
    #pragma unroll
    for (int j=0;j<8;j++){
      int k = q*32 + (lane>>4)*8 + j;
      float v = 0.f;
      if (k < 192) v = W[k*64 + n];
      else if (k < 195){ int tap = k-192; float s=0.f;
        for (int c=0;c<64;c++) s += W[(tap*64+c)*64 + n]; v = s; }
      o8[j] = (f16)v;
    }
    *(half8*)(ws + (size_t)tid*8) = *(half8*)o8;
  } else if (tid < 8192){
    int t2 = tid - 7168;             // nt*256 + q*64 + lane
    int lane = t2 % 64;
    int q    = (t2 / 64) % 4;
    int nt   = t2 / 256;
    int n = nt*16 + (lane & 15);
    f16 o8[8];
    #pragma unroll
    for (int j=0;j<8;j++){
      int k = q*32 + (lane>>4)*8 + j;      // < 128
      o8[j] = (f16)mlp_w[k*64 + n];
    }
    *(half8*)(ws + 57344 + (size_t)t2*8) = *(half8*)o8;
  }
}

// ---- layer 0 on VALU: lane = output channel; writes A (f16) and rsb (row channel-sums, f16)
template<int CIN, int CH0>
__device__ __forceinline__ void layer0(const f16* ib, f16* A, f16* rsb,
    const float* __restrict__ w0, const float* __restrict__ b0, int lane)
{
  float w[3*CIN];
  #pragma unroll
  for (int i=0;i<3*CIN;i++) w[i] = w0[i*64 + lane];
  float bias = b0[lane];
  #pragma unroll 1
  for (int p=0;p<G;p++){
    float x[11][4];
    #pragma unroll
    for (int i=0;i<11;i++){
      #pragma unroll
      for (int c=0;c<4;c++) x[i][c] = (float)ib[(p*11+i)*4 + c];
    }
    float vals[9];
    #pragma unroll
    for (int s=0;s<9;s++){
      float a = bias;
      #pragma unroll
      for (int t=0;t<3;t++){
        if (CIN == 1){
          a += (2.f * x[s+t][CH0]) * w[t];          // x + sum(x) = 2x for CIN=1
        } else {
          float ysum = x[s+t][CH0] + x[s+t][CH0+1] + x[s+t][CH0+2];
          #pragma unroll
          for (int c=0;c<CIN;c++) a += (x[s+t][CH0+c] + ysum) * w[t*CIN+c];
        }
      }
      vals[s] = fmaxf(a, 0.f);
    }
    float rs[9];
    #pragma unroll
    for (int s=0;s<9;s++) rs[s] = vals[s];
    #pragma unroll
    for (int m=1;m<64;m<<=1){
      #pragma unroll
      for (int s=0;s<9;s++) rs[s] += __shfl_xor(rs[s], m);
    }
    #pragma unroll
    for (int s=0;s<9;s++) A[(p*11+1+s)*AST + lane] = (f16)vals[s];
    if (lane == 0){
      #pragma unroll
      for (int s=0;s<9;s++) rsb[p*16+1+s] = (f16)rs[s];
    }
  }
}

// ---- conv layer via MFMA: src always A; dst A (in place) or compact Bc.
// All A/rsb reads happen in the MFMA phase, all writes in the epilogue -> in-place safe (single wave).
template<bool TO_COMPACT, bool WRITE_RS>
__device__ __forceinline__ void conv_layer(const f16* __restrict__ frag,
    const float* __restrict__ bias, f16* A, f16* Bc, f16* rsb, int lane)
{
  const int lo = lane & 15, qd = lane >> 4;
  float bn[4];
  #pragma unroll
  for (int nt=0;nt<4;nt++) bn[nt] = bias[nt*16 + lo];
  f32x4 acc[4][4];
  #pragma unroll
  for (int t=0;t<4;t++)
    #pragma unroll
    for (int nt=0;nt<4;nt++) acc[t][nt] = (f32x4){bn[nt],bn[nt],bn[nt],bn[nt]};

  int abase[4], rbase[4];
  #pragma unroll
  for (int t=0;t<4;t++){
    int m = t*16 + lo; if (m > 62) m = 62;      // row 63 is garbage (clamped, masked at store)
    int p = m/9, s = m - 9*p;
    abase[t] = ((p*11 + s)*AST)*2 + qd*16;      // byte addr; +tap*144 +(q&1)*64 are immediates
    rbase[t] = p*16 + s;
  }
  #pragma unroll
  for (int q=0;q<7;q++){
    half8 bv[4];
    #pragma unroll
    for (int nt=0;nt<4;nt++)
      bv[nt] = *(const half8*)(frag + ((nt*7 + q)*64 + lane)*8);
    #pragma unroll
    for (int t=0;t<4;t++){
      half8 av;
      if (q < 6){
        av = *(const half8*)((const char*)A + abase[t] + (q>>1)*(AST*2) + (q&1)*64);
      } else {
        const f16* rp = rsb + rbase[t];          // j=0..2 -> rs[s-1..s+1]; j>=3 times B=0
        av = (half8){rp[0], rp[1], rp[2], (f16)0, (f16)0, (f16)0, (f16)0, (f16)0};
      }
      #pragma unroll
      for (int nt=0;nt<4;nt++)
        acc[t][nt] = __builtin_amdgcn_mfma_f32_16x16x32_f16(av, bv[nt], acc[t][nt], 0, 0, 0);
    }
  }
  // epilogue: residual + relu + rowsum + store
  #pragma unroll
  for (int t=0;t<4;t++){
    #pragma unroll
    for (int r=0;r<4;r++){
      int mr = t*16 + qd*4 + r;
      int mc = mr > 62 ? 62 : mr;
      int pr = mc/9, sr = mc - 9*pr;
      bool vld = (mr < 63);
      f16* rowA = A + (pr*11 + 1 + sr)*AST;
      float tmp = 0.f, rnew[4];
      #pragma unroll
      for (int nt=0;nt<4;nt++){
        float rold = (float)rowA[nt*16 + lo];
        float v = fmaxf(acc[t][nt][r], 0.f) + rold;
        rnew[nt] = v; tmp += v;
      }
      if (WRITE_RS){
        tmp += __shfl_xor(tmp, 1); tmp += __shfl_xor(tmp, 2);
        tmp += __shfl_xor(tmp, 4); tmp += __shfl_xor(tmp, 8);
      }
      f16* dst = TO_COMPACT ? (Bc + (pr*9 + sr)*AST) : rowA;
      if (vld){
        #pragma unroll
        for (int nt=0;nt<4;nt++) dst[nt*16 + lo] = (f16)rnew[nt];
        if (WRITE_RS && lo == 0) rsb[pr*16 + 1 + sr] = (f16)tmp;
      }
    }
  }
}

__device__ __forceinline__ void mlp_out(const f16* __restrict__ frag,
    const float* __restrict__ mb, const f16* A, const f16* Bc,
    int lane, long pbase, float* __restrict__ out)
{
  const int lo = lane & 15, qd = lane >> 4;
  float bn[4];
  #pragma unroll
  for (int nt=0;nt<4;nt++) bn[nt] = mb[nt*16 + lo];
  f32x4 acc[4][4];
  #pragma unroll
  for (int t=0;t<4;t++)
    #pragma unroll
    for (int nt=0;nt<4;nt++) acc[t][nt] = (f32x4){bn[nt],bn[nt],bn[nt],bn[nt]};

  int aA[4], aB[4];
  #pragma unroll
  for (int t=0;t<4;t++){
    int m = t*16 + lo; if (m > 62) m = 62;
    int p = m/9, s = m - 9*p;
    aA[t] = ((p*11 + 1 + s)*AST)*2 + qd*16;     // nrm_e lives in padded A (+1 slot)
    aB[t] = ((p*9  +     s)*AST)*2 + qd*16;     // ang_e in compact Bc
  }
  #pragma unroll
  for (int q=0;q<4;q++){
    half8 bv[4];
    #pragma unroll
    for (int nt=0;nt<4;nt++)
      bv[nt] = *(const half8*)(frag + ((nt*4 + q)*64 + lane)*8);
    #pragma unroll
    for (int t=0;t<4;t++){
      half8 av = (q < 2)
        ? *(const half8*)((const char*)A  + aA[t] + q*64)
        : *(const half8*)((const char*)Bc + aB[t] + (q-2)*64);
      #pragma unroll
      for (int nt=0;nt<4;nt++)
        acc[t][nt] = __builtin_amdgcn_mfma_f32_16x16x32_f16(av, bv[nt], acc[t][nt], 0, 0, 0);
    }
  }
  #pragma unroll
  for (int t=0;t<4;t++){
    #pragma unroll
    for (int r=0;r<4;r++){
      int mr = t*16 + qd*4 + r;
      int mc = mr > 62 ? 62 : mr;
      int pr = mc/9, sr = mc - 9*pr;
      long pg = pbase + pr;
      if (mr < 63 && pg < Pv){
        float* op = out + ((long)(pg*9 + sr))*128 + lo;
        #pragma unroll
        for (int nt=0;nt<4;nt++) op[nt*16] = fmaxf(acc[t][nt][r], 0.f);
      }
    }
  }
}

__global__ __launch_bounds__(64, 2) void locse_main(
    const float* __restrict__ pc, const float* __restrict__ feats,
    const float* __restrict__ nw0, const float* __restrict__ nb0,
    const float* __restrict__ nb1, const float* __restrict__ nb2,
    const float* __restrict__ aw0, const float* __restrict__ ab0,
    const float* __restrict__ ab1, const float* __restrict__ ab2,
    const float* __restrict__ mb,  const f16* __restrict__ frag,
    float* __restrict__ out)
{
  __shared__ __align__(16) f16 A [G*11*AST];   // 11088 B, padded rows (slots 0,10 stay zero)
  __shared__ __align__(16) f16 Bc[G*9 *AST];   //  9072 B, ang_e compact
  __shared__ __align__(16) f16 ib [G*11*4];    //   616 B, layer-0 inputs (d0,d1,nrm,ang)
  __shared__ __align__(16) f16 rsb[G*16 + 48]; //   320 B, per-row channel-sums (slot 1+s)
  const int lane = threadIdx.x;
  const long pbase = (long)blockIdx.x * G;

  { // clears: A pads + ib + rsb must be zero
    const half8 z8 = {(f16)0,(f16)0,(f16)0,(f16)0,(f16)0,(f16)0,(f16)0,(f16)0};
    for (int i = lane; i < G*11*AST/8; i += 64) ((half8*)A)[i] = z8;
    for (int i = lane; i < G*11*4;     i += 64) ib[i]  = (f16)0;
    for (int i = lane; i < G*16+48;    i += 64) rsb[i] = (f16)0;
  }
  // derived features -> ib
  if (lane < 63){
    int p = lane/9, s = lane - 9*p;
    long pg = pbase + p;
    if (pg < Pv){
      const float4 v  = *(const float4*)(pc + (pg*9 + s)*4);
      const float4 cu = *(const float4*)(pc + (pg*9)*4);
      float d0 = cu.x - v.x, d1 = cu.y - v.y;
      float n2  = v.x*v.x + v.y*v.y;                        float nrm = n2  > 0.f ? sqrtf(n2)  : 0.f;
      float dn2 = d0*d0 + d1*d1;                            float dn  = dn2 > 0.f ? sqrtf(dn2) : 0.f;
      float cn2 = cu.x*cu.x + cu.y*cu.y + cu.z*cu.z + cu.w*cu.w;
      float cn  = cn2 > 0.f ? sqrtf(cn2) : 0.f;
      float ang = 1.f - fabsf((d0*cu.z + d1*cu.w) / (dn*cn + 1e-8f));
      f16* ip = ib + (p*11 + 1 + s)*4;
      ip[0]=(f16)d0; ip[1]=(f16)d1; ip[2]=(f16)nrm; ip[3]=(f16)ang;
    }
  }
  // ang encoder (channels d1,nrm,ang) -> Bc ; then nrm encoder (channel d0) stays in A
  layer0<3,1>(ib, A, rsb, aw0, ab0, lane);
  conv_layer<false,true >(frag + 0*14336, ab1, A, Bc, rsb, lane);
  conv_layer<true ,false>(frag + 1*14336, ab2, A, Bc, rsb, lane);
  layer0<1,0>(ib, A, rsb, nw0, nb0, lane);
  conv_layer<false,true >(frag + 2*14336, nb1, A, Bc, rsb, lane);
  conv_layer<false,false>(frag + 3*14336, nb2, A, Bc, rsb, lane);
  mlp_out(frag + 57344, mb, A, Bc, lane, pbase, out);

  // feats passthrough (float4, fully coalesced)
  {
    const float4* fs = (const float4*)pc; (void)fs;
    const float4* ff = (const float4*)feats + pbase*144;
    float4* op = (float4*)out;
    #pragma unroll 1
    for (int i=0;i<16;i++){
      int idx = i*64 + lane;                 // float4 units: 7*9*16 = 1008
      if (idx < G*9*16){
        int ps = idx >> 4, c4 = idx & 15;
        long pg = pbase + ps/9;
        if (pg < Pv)
          op[(pbase*9 + (long)ps)*32 + 16 + c4] = ff[(long)ps*16 + c4];
      }
    }
  }
}

extern "C" void kernel_launch(void* const* d_in, const int* in_sizes, int n_in,
                              void* d_out, int out_size, void* d_ws, size_t ws_size,
                              hipStream_t stream)
{
  const float* pc    = (const float*)d_in[0];
  const float* feats = (const float*)d_in[1];
  const float* nw0=(const float*)d_in[14]; const float* nb0=(const float*)d_in[15];
  const float* nw1=(const float*)d_in[16]; const float* nb1=(const float*)d_in[17];
  const float* nw2=(const float*)d_in[18]; const float* nb2=(const float*)d_in[19];
  const float* aw0=(const float*)d_in[20]; const float* ab0=(const float*)d_in[21];
  const float* aw1=(const float*)d_in[22]; const float* ab1=(const float*)d_in[23];
  const float* aw2=(const float*)d_in[24]; const float* ab2=(const float*)d_in[25];
  const float* mw =(const float*)d_in[26]; const float* mb =(const float*)d_in[27];
  f16* ws  = (f16*)d_ws;
  float* out = (float*)d_out;

  setup_frags<<<32, 256, 0, stream>>>(aw1, aw2, nw1, nw2, mw, ws);
  locse_main<<<NGRP, 64, 0, stream>>>(pc, feats, nw0, nb0, nb1, nb2,
                                      aw0, ab0, ab1, ab2, mb, ws, out);
}